// Round 11
// baseline (31974.243 us; speedup 1.0000x reference)
//
#include <hip/hip_runtime.h>

#define TT 2048
#define FF 64
#define HH 256
#define ZSTR 344  // zb row stride (ushorts)

typedef short short8 __attribute__((ext_vector_type(8)));
typedef float f32x4 __attribute__((ext_vector_type(4)));
typedef unsigned long long u64t;
typedef unsigned u32t;

// ws layout (bytes):
//  [0)        packed bf16 weights: WhhE@0 WihE@262144 WhhD@327680 WihD@589824 WoutP@655360 (ushort idx)
//  [1343488)  hb: [2 par][8 bb][256 U][8 rp] u64 tagged h-words = 32768*8 = 262144 B
#define WS_HB_B 1343488

__device__ inline unsigned short f2b(float f) {
  unsigned int u = __builtin_bit_cast(unsigned int, f);
  u += 0x7fffu + ((u >> 16) & 1u);
  return (unsigned short)(u >> 16);
}
__device__ inline u32t pk2(float a, float b) {
  return (u32t)f2b(a) | ((u32t)f2b(b) << 16);
}

// pack fragment-linear bf16 weights into ws (unchanged)
__global__ void prep_kernel(const float* __restrict__ Wih_e, const float* __restrict__ Whh_e,
                            const float* __restrict__ Wih_d, const float* __restrict__ Whh_d,
                            const float* __restrict__ Wout, unsigned short* __restrict__ ws) {
  int idx = blockIdx.x * blockDim.x + threadIdx.x;
  if (idx >= 83968) return;
  const float* src; unsigned short* dst; int q, kdim;
  if (idx < 32768)      { q = idx;         src = Whh_e; dst = ws + 0      + q * 8; kdim = HH; }
  else if (idx < 40960) { q = idx - 32768; src = Wih_e; dst = ws + 262144 + q * 8; kdim = FF; }
  else if (idx < 73728) { q = idx - 40960; src = Whh_d; dst = ws + 327680 + q * 8; kdim = HH; }
  else if (idx < 81920) { q = idx - 73728; src = Wih_d; dst = ws + 589824 + q * 8; kdim = FF; }
  else                  { q = idx - 81920; src = Wout;  dst = ws + 655360 + q * 8; kdim = HH; }
  int ksPerTile = (kdim == HH) ? 8 : 2;
  int per = ksPerTile * 64;
  int tile = q / per, rem = q % per;
  int ks = rem / 64, l = rem % 64;
  int col = tile * 16 + (l & 15);
  int k0 = ks * 32 + (l >> 4) * 8;
#pragma unroll
  for (int e = 0; e < 8; e++) dst[e] = f2b(src[col * kdim + k0 + e]);
}

// zero tagged exchange buffer each launch
__global__ void init_hb(u64t* __restrict__ hb) {
  int i = blockIdx.x * blockDim.x + threadIdx.x;
  if (i < 32768) hb[i] = 0ull;
}

// 64 blocks x 128 threads (2 waves). bb = bid>>3 (batch group), gg = bid&7 (32 hidden units).
// ALL weights LDS-resident (112KB): Whh slice 64KB + Wih 16KB + Wout 8KB + zb dbuf 22KB.
// Wave w owns all 4 gates for units 32gg+16w..+16. Own-slice + x MFMAs issued inside the
// exchange RTT window; tail after detect = 7 peer-ks x 4 MFMA + act.
// Exchange: r7-proven tagged u64 relaxed agent atomics, fence-free, parity double-buffered.
__global__ __launch_bounds__(128, 1) void lstm_kernel(
    const float* __restrict__ xg, const float* __restrict__ b_e,
    const float* __restrict__ b_d, const float* __restrict__ bout,
    const unsigned short* __restrict__ wsu, float* __restrict__ out,
    u64t* __restrict__ hb) {
  extern __shared__ unsigned short smem[];
  unsigned short* zbb      = smem;          // 2*16*ZSTR = 11008 ushorts
  unsigned short* wout_lds = smem + 11008;  // 8 ks x 64 x 8 = 4096
  unsigned short* whh_lds  = smem + 15104;  // 8 tl x 8 ks x 64 x 8 = 32768
  unsigned short* wih_lds  = smem + 47872;  // 8 tl x 2 j x 64 x 8 = 8192

  const int tid = threadIdx.x;
  const int l = tid & 63, w = tid >> 6;     // 2 waves
  const int ln = l & 15, lk = l >> 4;
  const int bb = blockIdx.x >> 3, gg = blockIdx.x & 7;
  const int b0 = bb * 16;

  if (gg < 4) {  // Wout tile gg (feats 16gg..16gg+16), staged once
    const short8* WoutP = (const short8*)(wsu + 655360);
    short8* wl = (short8*)wout_lds;
#pragma unroll
    for (int k = 0; k < 4; k++) wl[tid + 128 * k] = WoutP[gg * 512 + tid + 128 * k];
  }
  const float bo_ = (gg < 4) ? bout[16 * gg + ln] : 0.f;

  const int U = 32 * gg + 16 * w + ln;      // this lane's hidden unit

  // consumer: 14 words/thread over 224 peer units x 8 row-pairs (1792 = 14*128)
  int cidx[14], crow[14], cU[14];
#pragma unroll
  for (int k = 0; k < 14; k++) {
    int m = k * 128 + tid;
    int pu = m >> 3, rp = m & 7;
    int Up = pu + (pu >= 32 * gg ? 32 : 0);
    cidx[k] = (bb * 256 + Up) * 8 + rp;
    crow[k] = 2 * rp;
    cU[k] = Up;
  }
  const int p0 = (bb * 256 + U) * 8 + 2 * lk;  // producer words p0, p0+1

  float creg[4] = {0.f, 0.f, 0.f, 0.f};

  const int xrow = tid >> 3, xf0 = (tid & 7) * 8;
  const float* xrp = xg + (size_t)(b0 + xrow) * TT * FF + xf0;
  float4 xa = *(const float4*)xrp;            // x(0)
  float4 xb = *(const float4*)(xrp + 4);

  // prologue: zero zb[0] h region (2048 u32), stage x(0), prefetch x(1)
#pragma unroll
  for (int i = 0; i < 16; i++) {
    int q = i * 128 + tid;
    *(u32t*)&zbb[(q >> 7) * ZSTR + (q & 127) * 2] = 0u;
  }
  *(u32t*)&zbb[xrow * ZSTR + HH + xf0]     = pk2(xa.x, xa.y);
  *(u32t*)&zbb[xrow * ZSTR + HH + xf0 + 2] = pk2(xa.z, xa.w);
  *(u32t*)&zbb[xrow * ZSTR + HH + xf0 + 4] = pk2(xb.x, xb.y);
  *(u32t*)&zbb[xrow * ZSTR + HH + xf0 + 6] = pk2(xb.z, xb.w);
  xa = *(const float4*)(xrp + FF);
  xb = *(const float4*)(xrp + FF + 4);

  for (int ph = 0; ph < 2; ++ph) {
    const short8* WhhP = (const short8*)(wsu + (ph ? 327680 : 0));
    const short8* WihP = (const short8*)(wsu + (ph ? 589824 : 262144));
    const float* bias = ph ? b_d : b_e;

    __syncthreads();  // prior-phase LDS reads complete before restage
    {  // stage this block's Whh slice: 8 local tiles (4 gates x 2 subs) x 8 ks
      short8* wl = (short8*)whh_lds;
#pragma unroll
      for (int k = 0; k < 32; k++) {
        int i = tid + 128 * k;
        int lane = i & 63, ks = (i >> 6) & 7, tl = i >> 9;
        int c = (tl >> 1) * 16 + 2 * gg + (tl & 1);
        wl[i] = WhhP[(c * 8 + ks) * 64 + lane];
      }
      short8* wl2 = (short8*)wih_lds;
#pragma unroll
      for (int k = 0; k < 8; k++) {
        int i = tid + 128 * k;
        int lane = i & 63, j = (i >> 6) & 1, tl = i >> 7;
        int c = (tl >> 1) * 16 + 2 * gg + (tl & 1);
        wl2[i] = WihP[(c * 2 + j) * 64 + lane];
      }
    }
    float bact[4];
#pragma unroll
    for (int g = 0; g < 4; g++) bact[g] = bias[g * 256 + U];
    __syncthreads();  // weights staged

#pragma unroll 1
    for (int ti = 0; ti < TT; ++ti) {
      const int it = ph * TT + ti;
      const int t = ph ? (TT - 1 - ti) : ti;
      unsigned short* zc = zbb + (it & 1) * (16 * ZSTR);
      unsigned short* zn = zbb + ((it & 1) ^ 1) * (16 * ZSTR);

      const short8* WH = (const short8*)whh_lds;
      const short8* WX = (const short8*)wih_lds;

      // own-slice + x fragments and their MFMAs (run inside the exchange RTT window)
      short8 aOwn = *(const short8*)&zc[ln * ZSTR + gg * 32 + lk * 8];
      short8 aX0  = *(const short8*)&zc[ln * ZSTR + 256 + lk * 8];
      short8 aX1  = *(const short8*)&zc[ln * ZSTR + 288 + lk * 8];

      f32x4 acc[4];
#pragma unroll
      for (int g = 0; g < 4; g++) acc[g] = f32x4{0.f, 0.f, 0.f, 0.f};
#pragma unroll
      for (int g = 0; g < 4; g++) {
        const int tl = g * 2 + w;
        acc[g] = __builtin_amdgcn_mfma_f32_16x16x32_bf16(aOwn, WH[(tl * 8 + gg) * 64 + l], acc[g], 0, 0, 0);
        acc[g] = __builtin_amdgcn_mfma_f32_16x16x32_bf16(aX0,  WX[(tl * 2 + 0) * 64 + l], acc[g], 0, 0, 0);
        acc[g] = __builtin_amdgcn_mfma_f32_16x16x32_bf16(aX1,  WX[(tl * 2 + 1) * 64 + l], acc[g], 0, 0, 0);
      }

      // spin on 14 peer words (tagged, relaxed agent — r7-proven), unpack into zc
      if (it) {
        const u64t* base = hb + (size_t)(it & 1) * 16384;
        u64t v[14];
        bool d[14];
#pragma unroll
        for (int k = 0; k < 14; k++) { v[k] = 0; d[k] = false; }
        for (;;) {
          bool all = true;
#pragma unroll
          for (int k = 0; k < 14; k++) {
            if (!d[k]) {
              u64t x = __hip_atomic_load(base + cidx[k], __ATOMIC_RELAXED, __HIP_MEMORY_SCOPE_AGENT);
              if ((u32t)x == (u32t)it) { v[k] = x; d[k] = true; } else all = false;
            }
          }
          if (all) break;
        }
#pragma unroll
        for (int k = 0; k < 14; k++) {
          zc[crow[k] * ZSTR + cU[k]]       = (unsigned short)(v[k] >> 32);
          zc[(crow[k] + 1) * ZSTR + cU[k]] = (unsigned short)(v[k] >> 48);
        }
      }
      __syncthreads();  // B1: full z assembled

      // peer-slice fragments + MFMAs (the critical tail)
      short8 aP[7];
#pragma unroll
      for (int pk = 0; pk < 7; pk++) {
        int ks = pk + (pk >= gg ? 1 : 0);
        aP[pk] = *(const short8*)&zc[ln * ZSTR + ks * 32 + lk * 8];
      }
#pragma unroll
      for (int pk = 0; pk < 7; pk++) {
        int ks = pk + (pk >= gg ? 1 : 0);
#pragma unroll
        for (int g = 0; g < 4; g++) {
          const int tl = g * 2 + w;
          acc[g] = __builtin_amdgcn_mfma_f32_16x16x32_bf16(aP[pk], WH[(tl * 8 + ks) * 64 + l], acc[g], 0, 0, 0);
        }
      }

      // wave-local activation: lane holds i,f,g,o for unit U, rows 4lk+r
      unsigned short hu[4];
#pragma unroll
      for (int r = 0; r < 4; r++) {
        float gi = acc[0][r] + bact[0];
        float gf = acc[1][r] + bact[1];
        float gG = acc[2][r] + bact[2];
        float go = acc[3][r] + bact[3];
        float si = 1.f / (1.f + __expf(-gi));
        float sf = 1.f / (1.f + __expf(-gf));
        float tg = 1.f - 2.f / (__expf(2.f * gG) + 1.f);
        float so = 1.f / (1.f + __expf(-go));
        float cn = sf * creg[r] + si * tg;
        creg[r] = cn;
        float hn = so * (1.f - 2.f / (__expf(2.f * cn) + 1.f));
        hu[r] = f2b(hn);
      }

      {  // publish h(it+1) FIRST (peers' critical path), relaxed agent, fence-free
        u64t* bp = hb + (size_t)((it + 1) & 1) * 16384;
        const u64t tag = (u64t)(u32t)(it + 1);
        __hip_atomic_store(bp + p0,     tag | ((u64t)((u32t)hu[0] | ((u32t)hu[1] << 16)) << 32),
                           __ATOMIC_RELAXED, __HIP_MEMORY_SCOPE_AGENT);
        __hip_atomic_store(bp + p0 + 1, tag | ((u64t)((u32t)hu[2] | ((u32t)hu[3] << 16)) << 32),
                           __ATOMIC_RELAXED, __HIP_MEMORY_SCOPE_AGENT);
      }

      // stage own h(it+1) into next zb
      zn[(4 * lk + 0) * ZSTR + U] = hu[0];
      zn[(4 * lk + 1) * ZSTR + U] = hu[1];
      zn[(4 * lk + 2) * ZSTR + U] = hu[2];
      zn[(4 * lk + 3) * ZSTR + U] = hu[3];

      // decoder output (gg<4, rotating wave): out[:,t] = h(it) @ Wout^T + bout
      if (ph == 1 && gg < 4 && w == (ti & 1)) {
        const short8* WO = (const short8*)wout_lds;
        f32x4 oa = {0.f, 0.f, 0.f, 0.f};
        oa = __builtin_amdgcn_mfma_f32_16x16x32_bf16(aOwn, WO[gg * 64 + l], oa, 0, 0, 0);
#pragma unroll
        for (int pk = 0; pk < 7; pk++) {
          int ks = pk + (pk >= gg ? 1 : 0);
          oa = __builtin_amdgcn_mfma_f32_16x16x32_bf16(aP[pk], WO[ks * 64 + l], oa, 0, 0, 0);
        }
#pragma unroll
        for (int r = 0; r < 4; r++)
          out[((size_t)(b0 + 4 * lk + r) * TT + t) * FF + 16 * gg + ln] = oa[r] + bo_;
      }

      // stage x(t+1) into next zb; prefetch x(t+2)
      *(u32t*)&zn[xrow * ZSTR + HH + xf0]     = pk2(xa.x, xa.y);
      *(u32t*)&zn[xrow * ZSTR + HH + xf0 + 2] = pk2(xa.z, xa.w);
      *(u32t*)&zn[xrow * ZSTR + HH + xf0 + 4] = pk2(xb.x, xb.y);
      *(u32t*)&zn[xrow * ZSTR + HH + xf0 + 6] = pk2(xb.z, xb.w);
      {
        int it2 = it + 2; if (it2 >= 2 * TT) it2 = 0;
        int t2 = (it2 < TT) ? it2 : (2 * TT - 1 - it2);
        xa = *(const float4*)(xrp + (size_t)t2 * FF);
        xb = *(const float4*)(xrp + (size_t)t2 * FF + 4);
      }
      __syncthreads();  // B2: next zb staged; zc reads done
    }
  }
}

extern "C" void kernel_launch(void* const* d_in, const int* in_sizes, int n_in,
                              void* d_out, int out_size, void* d_ws, size_t ws_size,
                              hipStream_t stream) {
  const float* ts    = (const float*)d_in[0];
  const float* Wih_e = (const float*)d_in[1];
  const float* Whh_e = (const float*)d_in[2];
  const float* b_e   = (const float*)d_in[3];
  const float* Wih_d = (const float*)d_in[4];
  const float* Whh_d = (const float*)d_in[5];
  const float* b_d   = (const float*)d_in[6];
  const float* Wout  = (const float*)d_in[7];
  const float* bout  = (const float*)d_in[8];
  unsigned short* ws = (unsigned short*)d_ws;
  float* out = (float*)d_out;
  u64t* hb = (u64t*)((char*)d_ws + WS_HB_B);

  const int ldsBytes = 56064 * 2;  // 112128 B -> 1 block/CU
  (void)hipFuncSetAttribute((const void*)lstm_kernel,
                            hipFuncAttributeMaxDynamicSharedMemorySize, ldsBytes);

  prep_kernel<<<328, 256, 0, stream>>>(Wih_e, Whh_e, Wih_d, Whh_d, Wout, ws);
  init_hb<<<64, 512, 0, stream>>>(hb);
  lstm_kernel<<<64, 128, ldsBytes, stream>>>(ts, b_e, b_d, bout, ws, out, hb);
}

// Round 12
// 13272.188 us; speedup vs baseline: 2.4091x; 2.4091x over previous
//
#include <hip/hip_runtime.h>

#define TT 2048
#define FF 64
#define HH 256
#define ZSTR 336  // zb row stride (ushorts), 672B: 16B-aligned, ~4-way bank aliasing

typedef short short8 __attribute__((ext_vector_type(8)));
typedef float f32x4 __attribute__((ext_vector_type(4)));
typedef unsigned long long u64t;
typedef unsigned u32t;

// ws layout (bytes):
//  [0)        packed bf16 weights: WhhE@0 WihE@262144 WhhD@327680 WihD@589824 WoutP@655360 (ushort idx)
//  [1343488)  hb: [2 par][8 bb][256 U][8 rp] u64 tagged h-words = 32768*8 = 262144 B
#define WS_HB_B 1343488

__device__ inline unsigned short f2b(float f) {
  unsigned int u = __builtin_bit_cast(unsigned int, f);
  u += 0x7fffu + ((u >> 16) & 1u);
  return (unsigned short)(u >> 16);
}
__device__ inline u32t pk2(float a, float b) {
  return (u32t)f2b(a) | ((u32t)f2b(b) << 16);
}

// pack fragment-linear bf16 weights into ws (unchanged)
__global__ void prep_kernel(const float* __restrict__ Wih_e, const float* __restrict__ Whh_e,
                            const float* __restrict__ Wih_d, const float* __restrict__ Whh_d,
                            const float* __restrict__ Wout, unsigned short* __restrict__ ws) {
  int idx = blockIdx.x * blockDim.x + threadIdx.x;
  if (idx >= 83968) return;
  const float* src; unsigned short* dst; int q, kdim;
  if (idx < 32768)      { q = idx;         src = Whh_e; dst = ws + 0      + q * 8; kdim = HH; }
  else if (idx < 40960) { q = idx - 32768; src = Wih_e; dst = ws + 262144 + q * 8; kdim = FF; }
  else if (idx < 73728) { q = idx - 40960; src = Whh_d; dst = ws + 327680 + q * 8; kdim = HH; }
  else if (idx < 81920) { q = idx - 73728; src = Wih_d; dst = ws + 589824 + q * 8; kdim = FF; }
  else                  { q = idx - 81920; src = Wout;  dst = ws + 655360 + q * 8; kdim = HH; }
  int ksPerTile = (kdim == HH) ? 8 : 2;
  int per = ksPerTile * 64;
  int tile = q / per, rem = q % per;
  int ks = rem / 64, l = rem % 64;
  int col = tile * 16 + (l & 15);
  int k0 = ks * 32 + (l >> 4) * 8;
#pragma unroll
  for (int e = 0; e < 8; e++) dst[e] = f2b(src[col * kdim + k0 + e]);
}

// zero tagged exchange buffer each launch
__global__ void init_hb(u64t* __restrict__ hb) {
  int i = blockIdx.x * blockDim.x + threadIdx.x;
  if (i < 32768) hb[i] = 0ull;
}

// 32 blocks x 256 threads (4 waves) — r7's proven sync geometry (8 bb x 4 gg, fan-in 3).
// Whh slice (128KB) LDS-resident: remat-safe backing store (ds_read ~12cy vs L2 ~200cy).
// Wave w owns all 4 gates for units 64gg+16w..+16. Peer-B preloaded to regs inside the
// RTT window (sched_barrier-pinned); tail after detect = 6 A-reads + 24 MFMA + act.
// Exchange: tagged u64 relaxed agent atomics, fence-free, parity double-buffered (proven r5-r11).
__global__ __launch_bounds__(256, 1) void lstm_kernel(
    const float* __restrict__ xg, const float* __restrict__ b_e,
    const float* __restrict__ b_d, const float* __restrict__ bout,
    const unsigned short* __restrict__ wsu, float* __restrict__ out,
    u64t* __restrict__ hb) {
  extern __shared__ unsigned short smem[];
  unsigned short* zbb     = smem;          // 2*16*ZSTR = 10752 ushorts (21504B)
  unsigned short* whh_lds = smem + 10752;  // 16 tl x 8 ks x 64 x 8 = 65536 ushorts (131072B)

  const int tid = threadIdx.x;
  const int l = tid & 63, w = tid >> 6;    // 4 waves
  const int ln = l & 15, lk = l >> 4;
  const int bb = blockIdx.x & 7, gg = blockIdx.x >> 3;
  const int b0 = bb * 16;

  const int U = 64 * gg + 16 * w + ln;     // this lane's hidden unit
  const float bo_ = bout[16 * gg + ln];

  // consumer: 6 words/thread over 192 peer units x 8 row-pairs (1536 = 6*256)
  int cidx[6], crow[6], cU[6];
#pragma unroll
  for (int k = 0; k < 6; k++) {
    int m = k * 256 + tid;
    int pu = m >> 3, rp = m & 7;
    int Up = pu + (pu >= 64 * gg ? 64 : 0);
    cidx[k] = (bb * 256 + Up) * 8 + rp;
    crow[k] = 2 * rp;
    cU[k] = Up;
  }
  const int p0 = (bb * 256 + U) * 8 + 2 * lk;  // producer words p0, p0+1

  float creg[4] = {0.f, 0.f, 0.f, 0.f};

  const int xrow = tid >> 4, xf = (tid & 15) * 4;
  const float* xrp = xg + (size_t)(b0 + xrow) * TT * FF + xf;
  float4 xv = *(const float4*)xrp;  // x(0)

  // prologue: zero zb[0] h region (2048 u32), stage x(0), prefetch x(1)
#pragma unroll
  for (int i = 0; i < 8; i++) {
    int q = i * 256 + tid;
    *(u32t*)&zbb[(q >> 7) * ZSTR + (q & 127) * 2] = 0u;
  }
  *(u32t*)&zbb[xrow * ZSTR + HH + xf]     = pk2(xv.x, xv.y);
  *(u32t*)&zbb[xrow * ZSTR + HH + xf + 2] = pk2(xv.z, xv.w);
  xv = *(const float4*)(xrp + FF);  // x(1)

  for (int ph = 0; ph < 2; ++ph) {
    const short8* WhhP = (const short8*)(wsu + (ph ? 327680 : 0));
    const short8* WihP = (const short8*)(wsu + (ph ? 589824 : 262144));
    const float* bias = ph ? b_d : b_e;

    __syncthreads();  // prior-phase LDS reads complete
    {  // stage Whh slice: 16 local tiles (4 gates x 4 waves) x 8 ks x 1KB = 128KB
      short8* wl = (short8*)whh_lds;
#pragma unroll
      for (int k = 0; k < 32; k++) {
        int i = tid + 256 * k;
        int lane = i & 63, ks = (i >> 6) & 7, tl = i >> 9;
        int c = (tl >> 2) * 16 + 4 * gg + (tl & 3);
        wl[i] = WhhP[(c * 8 + ks) * 64 + lane];
      }
    }
    // Wih fragments: loop-invariant (compiler hoists to regs or remats from L2 — both fine)
    short8 rX[4][2];
#pragma unroll
    for (int g = 0; g < 4; g++)
#pragma unroll
      for (int j = 0; j < 2; j++)
        rX[g][j] = WihP[((g * 16 + 4 * gg + w) * 2 + j) * 64 + l];

    float bact[4];
#pragma unroll
    for (int g = 0; g < 4; g++) bact[g] = bias[g * 256 + U];
    __syncthreads();  // weights staged

#pragma unroll 1
    for (int ti = 0; ti < TT; ++ti) {
      const int it = ph * TT + ti;
      const int t = ph ? (TT - 1 - ti) : ti;
      unsigned short* zc = zbb + (it & 1) * (16 * ZSTR);
      unsigned short* zn = zbb + ((it & 1) ^ 1) * (16 * ZSTR);
      const short8* WH = (const short8*)whh_lds;

      // peer-B preload into regs (96 VGPRs) — LDS reads overlap the spin window
      short8 pB[4][6];
#pragma unroll
      for (int g = 0; g < 4; g++)
#pragma unroll
        for (int pk = 0; pk < 6; pk++) {
          int ks = pk + (pk >= 2 * gg ? 2 : 0);
          pB[g][pk] = WH[((g * 4 + w) * 8 + ks) * 64 + l];
        }

      // own + x fragments and their 16 MFMAs (inside the RTT window)
      short8 aOwn0 = *(const short8*)&zc[ln * ZSTR + (2 * gg) * 32 + lk * 8];
      short8 aOwn1 = *(const short8*)&zc[ln * ZSTR + (2 * gg + 1) * 32 + lk * 8];
      short8 aX0   = *(const short8*)&zc[ln * ZSTR + 256 + lk * 8];
      short8 aX1   = *(const short8*)&zc[ln * ZSTR + 288 + lk * 8];

      f32x4 acc[4];
#pragma unroll
      for (int g = 0; g < 4; g++) acc[g] = f32x4{0.f, 0.f, 0.f, 0.f};
#pragma unroll
      for (int g = 0; g < 4; g++) {
        short8 oB0 = WH[((g * 4 + w) * 8 + 2 * gg) * 64 + l];
        short8 oB1 = WH[((g * 4 + w) * 8 + 2 * gg + 1) * 64 + l];
        acc[g] = __builtin_amdgcn_mfma_f32_16x16x32_bf16(aOwn0, oB0, acc[g], 0, 0, 0);
        acc[g] = __builtin_amdgcn_mfma_f32_16x16x32_bf16(aOwn1, oB1, acc[g], 0, 0, 0);
        acc[g] = __builtin_amdgcn_mfma_f32_16x16x32_bf16(aX0, rX[g][0], acc[g], 0, 0, 0);
        acc[g] = __builtin_amdgcn_mfma_f32_16x16x32_bf16(aX1, rX[g][1], acc[g], 0, 0, 0);
      }
      __builtin_amdgcn_sched_barrier(0);  // pin preloads + own MFMAs above the spin

      // spin on 6 peer words (tagged, relaxed agent — proven), unpack into zc
      if (it) {
        const u64t* base = hb + (size_t)(it & 1) * 16384;
        u64t v0 = 0, v1 = 0, v2 = 0, v3 = 0, v4 = 0, v5 = 0;
        bool d0 = false, d1 = false, d2 = false, d3 = false, d4 = false, d5 = false;
        do {
          if (!d0) { v0 = __hip_atomic_load(base + cidx[0], __ATOMIC_RELAXED, __HIP_MEMORY_SCOPE_AGENT);
                     d0 = ((u32t)v0 == (u32t)it); }
          if (!d1) { v1 = __hip_atomic_load(base + cidx[1], __ATOMIC_RELAXED, __HIP_MEMORY_SCOPE_AGENT);
                     d1 = ((u32t)v1 == (u32t)it); }
          if (!d2) { v2 = __hip_atomic_load(base + cidx[2], __ATOMIC_RELAXED, __HIP_MEMORY_SCOPE_AGENT);
                     d2 = ((u32t)v2 == (u32t)it); }
          if (!d3) { v3 = __hip_atomic_load(base + cidx[3], __ATOMIC_RELAXED, __HIP_MEMORY_SCOPE_AGENT);
                     d3 = ((u32t)v3 == (u32t)it); }
          if (!d4) { v4 = __hip_atomic_load(base + cidx[4], __ATOMIC_RELAXED, __HIP_MEMORY_SCOPE_AGENT);
                     d4 = ((u32t)v4 == (u32t)it); }
          if (!d5) { v5 = __hip_atomic_load(base + cidx[5], __ATOMIC_RELAXED, __HIP_MEMORY_SCOPE_AGENT);
                     d5 = ((u32t)v5 == (u32t)it); }
        } while (!(d0 && d1 && d2 && d3 && d4 && d5));
        zc[crow[0] * ZSTR + cU[0]] = (unsigned short)(v0 >> 32);
        zc[(crow[0] + 1) * ZSTR + cU[0]] = (unsigned short)(v0 >> 48);
        zc[crow[1] * ZSTR + cU[1]] = (unsigned short)(v1 >> 32);
        zc[(crow[1] + 1) * ZSTR + cU[1]] = (unsigned short)(v1 >> 48);
        zc[crow[2] * ZSTR + cU[2]] = (unsigned short)(v2 >> 32);
        zc[(crow[2] + 1) * ZSTR + cU[2]] = (unsigned short)(v2 >> 48);
        zc[crow[3] * ZSTR + cU[3]] = (unsigned short)(v3 >> 32);
        zc[(crow[3] + 1) * ZSTR + cU[3]] = (unsigned short)(v3 >> 48);
        zc[crow[4] * ZSTR + cU[4]] = (unsigned short)(v4 >> 32);
        zc[(crow[4] + 1) * ZSTR + cU[4]] = (unsigned short)(v4 >> 48);
        zc[crow[5] * ZSTR + cU[5]] = (unsigned short)(v5 >> 32);
        zc[(crow[5] + 1) * ZSTR + cU[5]] = (unsigned short)(v5 >> 48);
      }
      __syncthreads();  // B1: full z assembled

      // critical tail: 6 A-reads + 24 MFMA (B already in regs)
      short8 aP[6];
#pragma unroll
      for (int pk = 0; pk < 6; pk++) {
        int ks = pk + (pk >= 2 * gg ? 2 : 0);
        aP[pk] = *(const short8*)&zc[ln * ZSTR + ks * 32 + lk * 8];
      }
#pragma unroll
      for (int pk = 0; pk < 6; pk++)
#pragma unroll
        for (int g = 0; g < 4; g++)
          acc[g] = __builtin_amdgcn_mfma_f32_16x16x32_bf16(aP[pk], pB[g][pk], acc[g], 0, 0, 0);

      // wave-local activation: lane holds i,f,g,o for unit U, rows 4lk+r
      unsigned short hu[4];
#pragma unroll
      for (int r = 0; r < 4; r++) {
        float gi = acc[0][r] + bact[0];
        float gf = acc[1][r] + bact[1];
        float gG = acc[2][r] + bact[2];
        float go = acc[3][r] + bact[3];
        float si = 1.f / (1.f + __expf(-gi));
        float sf = 1.f / (1.f + __expf(-gf));
        float tg = 1.f - 2.f / (__expf(2.f * gG) + 1.f);
        float so = 1.f / (1.f + __expf(-go));
        float cn = sf * creg[r] + si * tg;
        creg[r] = cn;
        float hn = so * (1.f - 2.f / (__expf(2.f * cn) + 1.f));
        hu[r] = f2b(hn);
      }

      {  // publish h(it+1) FIRST (peers' critical path)
        u64t* bp = hb + (size_t)((it + 1) & 1) * 16384;
        const u64t tag = (u64t)(u32t)(it + 1);
        __hip_atomic_store(bp + p0,     tag | ((u64t)((u32t)hu[0] | ((u32t)hu[1] << 16)) << 32),
                           __ATOMIC_RELAXED, __HIP_MEMORY_SCOPE_AGENT);
        __hip_atomic_store(bp + p0 + 1, tag | ((u64t)((u32t)hu[2] | ((u32t)hu[3] << 16)) << 32),
                           __ATOMIC_RELAXED, __HIP_MEMORY_SCOPE_AGENT);
      }

      // stage own h(it+1) into next zb
      zn[(4 * lk + 0) * ZSTR + U] = hu[0];
      zn[(4 * lk + 1) * ZSTR + U] = hu[1];
      zn[(4 * lk + 2) * ZSTR + U] = hu[2];
      zn[(4 * lk + 3) * ZSTR + U] = hu[3];

      // decoder output (rotating wave, off critical path): out[:,t] = h(it) @ Wout^T + bout
      if (ph == 1 && w == (ti & 3)) {
        const short8* WoP = (const short8*)(wsu + 655360);
        f32x4 oa = {0.f, 0.f, 0.f, 0.f};
        oa = __builtin_amdgcn_mfma_f32_16x16x32_bf16(aOwn0, WoP[gg * 512 + (2 * gg) * 64 + l], oa, 0, 0, 0);
        oa = __builtin_amdgcn_mfma_f32_16x16x32_bf16(aOwn1, WoP[gg * 512 + (2 * gg + 1) * 64 + l], oa, 0, 0, 0);
#pragma unroll
        for (int pk = 0; pk < 6; pk++) {
          int ks = pk + (pk >= 2 * gg ? 2 : 0);
          oa = __builtin_amdgcn_mfma_f32_16x16x32_bf16(aP[pk], WoP[gg * 512 + ks * 64 + l], oa, 0, 0, 0);
        }
#pragma unroll
        for (int r = 0; r < 4; r++)
          out[((size_t)(b0 + 4 * lk + r) * TT + t) * FF + 16 * gg + ln] = oa[r] + bo_;
      }

      // stage x(t+1) into next zb; prefetch x(t+2)
      *(u32t*)&zn[xrow * ZSTR + HH + xf]     = pk2(xv.x, xv.y);
      *(u32t*)&zn[xrow * ZSTR + HH + xf + 2] = pk2(xv.z, xv.w);
      {
        int it2 = it + 2; if (it2 >= 2 * TT) it2 = 0;
        int t2 = (it2 < TT) ? it2 : (2 * TT - 1 - it2);
        xv = *(const float4*)(xrp + (size_t)t2 * FF);
      }
      __syncthreads();  // B2: next zb staged; zc reads done
    }
  }
}

extern "C" void kernel_launch(void* const* d_in, const int* in_sizes, int n_in,
                              void* d_out, int out_size, void* d_ws, size_t ws_size,
                              hipStream_t stream) {
  const float* ts    = (const float*)d_in[0];
  const float* Wih_e = (const float*)d_in[1];
  const float* Whh_e = (const float*)d_in[2];
  const float* b_e   = (const float*)d_in[3];
  const float* Wih_d = (const float*)d_in[4];
  const float* Whh_d = (const float*)d_in[5];
  const float* b_d   = (const float*)d_in[6];
  const float* Wout  = (const float*)d_in[7];
  const float* bout  = (const float*)d_in[8];
  unsigned short* ws = (unsigned short*)d_ws;
  float* out = (float*)d_out;
  u64t* hb = (u64t*)((char*)d_ws + WS_HB_B);

  const int ldsBytes = (10752 + 65536) * 2;  // 152576 B
  (void)hipFuncSetAttribute((const void*)lstm_kernel,
                            hipFuncAttributeMaxDynamicSharedMemorySize, ldsBytes);

  prep_kernel<<<328, 256, 0, stream>>>(Wih_e, Whh_e, Wih_d, Whh_d, Wout, ws);
  init_hb<<<64, 512, 0, stream>>>(hb);
  lstm_kernel<<<32, 256, ldsBytes, stream>>>(ts, b_e, b_d, bout, ws, out, hb);
}

// Round 13
// 11390.574 us; speedup vs baseline: 2.8071x; 1.1652x over previous
//
#include <hip/hip_runtime.h>

#define TT 2048
#define FF 64
#define HH 256
#define ZSTR 328  // zb row stride (ushorts), 656B: 16B-aligned, bank-stride 4 (~2-way, free)

typedef short short8 __attribute__((ext_vector_type(8)));
typedef float f32x4 __attribute__((ext_vector_type(4)));
typedef unsigned long long u64t;
typedef unsigned u32t;

// ws layout (bytes):
//  [0)        packed bf16 weights: WhhE@0 WihE@262144 WhhD@327680 WihD@589824 WoutP@655360 (ushort idx)
//  [1343488)  hb: [2 par][8 bb][256 U][8 rp] u64 tagged h-words = 32768*8 = 262144 B
#define WS_HB_B 1343488

__device__ inline unsigned short f2b(float f) {
  unsigned int u = __builtin_bit_cast(unsigned int, f);
  u += 0x7fffu + ((u >> 16) & 1u);
  return (unsigned short)(u >> 16);
}
__device__ inline u32t pk2(float a, float b) {
  return (u32t)f2b(a) | ((u32t)f2b(b) << 16);
}

// pack fragment-linear bf16 weights into ws (unchanged)
__global__ void prep_kernel(const float* __restrict__ Wih_e, const float* __restrict__ Whh_e,
                            const float* __restrict__ Wih_d, const float* __restrict__ Whh_d,
                            const float* __restrict__ Wout, unsigned short* __restrict__ ws) {
  int idx = blockIdx.x * blockDim.x + threadIdx.x;
  if (idx >= 83968) return;
  const float* src; unsigned short* dst; int q, kdim;
  if (idx < 32768)      { q = idx;         src = Whh_e; dst = ws + 0      + q * 8; kdim = HH; }
  else if (idx < 40960) { q = idx - 32768; src = Wih_e; dst = ws + 262144 + q * 8; kdim = FF; }
  else if (idx < 73728) { q = idx - 40960; src = Whh_d; dst = ws + 327680 + q * 8; kdim = HH; }
  else if (idx < 81920) { q = idx - 73728; src = Wih_d; dst = ws + 589824 + q * 8; kdim = FF; }
  else                  { q = idx - 81920; src = Wout;  dst = ws + 655360 + q * 8; kdim = HH; }
  int ksPerTile = (kdim == HH) ? 8 : 2;
  int per = ksPerTile * 64;
  int tile = q / per, rem = q % per;
  int ks = rem / 64, l = rem % 64;
  int col = tile * 16 + (l & 15);
  int k0 = ks * 32 + (l >> 4) * 8;
#pragma unroll
  for (int e = 0; e < 8; e++) dst[e] = f2b(src[col * kdim + k0 + e]);
}

// zero tagged exchange buffer each launch
__global__ void init_hb(u64t* __restrict__ hb) {
  int i = blockIdx.x * blockDim.x + threadIdx.x;
  if (i < 32768) hb[i] = 0ull;
}

// 32 blocks x 256 threads (4 waves) — r7 sync geometry (8 bb x 4 gg, fan-in 3).
// Whh slice (128KB) + Wout tile (8KB) LDS-resident; B-fragments hoisted to registers
// once per phase (LDS is the cheap remat backing — no per-step forced reread, no fence).
// Wave w owns all 4 gates for units 64gg+16w..+16; wave-local activation.
// Exchange: tagged u64 relaxed agent atomics, fence-free, parity double-buffered (proven).
__global__ __launch_bounds__(256, 1) void lstm_kernel(
    const float* __restrict__ xg, const float* __restrict__ b_e,
    const float* __restrict__ b_d, const float* __restrict__ bout,
    const unsigned short* __restrict__ wsu, float* __restrict__ out,
    u64t* __restrict__ hb) {
  extern __shared__ unsigned short smem[];
  unsigned short* zbb      = smem;          // 2*16*ZSTR = 10496 ushorts (20992B)
  unsigned short* wout_lds = smem + 10496;  // 8 ks x 64 x 8 = 4096 (8192B)
  unsigned short* whh_lds  = smem + 14592;  // 16 tl x 8 ks x 64 x 8 = 65536 (131072B)

  const int tid = threadIdx.x;
  const int l = tid & 63, w = tid >> 6;    // 4 waves
  const int ln = l & 15, lk = l >> 4;
  const int bb = blockIdx.x & 7, gg = blockIdx.x >> 3;
  const int b0 = bb * 16;

  const int U = 64 * gg + 16 * w + ln;     // this lane's hidden unit
  const float bo_ = bout[16 * gg + ln];

  {  // stage Wout tile gg once
    const short8* WoutP = (const short8*)(wsu + 655360);
    short8* wl = (short8*)wout_lds;
    wl[tid] = WoutP[gg * 512 + tid];
    wl[tid + 256] = WoutP[gg * 512 + tid + 256];
  }

  // consumer: 6 words/thread over 192 peer units x 8 row-pairs (1536 = 6*256)
  int cidx[6], crow[6], cU[6];
#pragma unroll
  for (int k = 0; k < 6; k++) {
    int m = k * 256 + tid;
    int pu = m >> 3, rp = m & 7;
    int Up = pu + (pu >= 64 * gg ? 64 : 0);
    cidx[k] = (bb * 256 + Up) * 8 + rp;
    crow[k] = 2 * rp;
    cU[k] = Up;
  }
  const int p0 = (bb * 256 + U) * 8 + 2 * lk;  // producer words p0, p0+1

  float creg[4] = {0.f, 0.f, 0.f, 0.f};

  const int xrow = tid >> 4, xf = (tid & 15) * 4;
  const float* xrp = xg + (size_t)(b0 + xrow) * TT * FF + xf;
  float4 xv = *(const float4*)xrp;  // x(0)

  // prologue: zero zb[0] h region (2048 u32), stage x(0), prefetch x(1)
#pragma unroll
  for (int i = 0; i < 8; i++) {
    int q = i * 256 + tid;
    *(u32t*)&zbb[(q >> 7) * ZSTR + (q & 127) * 2] = 0u;
  }
  *(u32t*)&zbb[xrow * ZSTR + HH + xf]     = pk2(xv.x, xv.y);
  *(u32t*)&zbb[xrow * ZSTR + HH + xf + 2] = pk2(xv.z, xv.w);
  xv = *(const float4*)(xrp + FF);  // x(1)

  for (int ph = 0; ph < 2; ++ph) {
    const short8* WhhP = (const short8*)(wsu + (ph ? 327680 : 0));
    const short8* WihP = (const short8*)(wsu + (ph ? 589824 : 262144));
    const float* bias = ph ? b_d : b_e;

    __syncthreads();  // prior-phase LDS reads complete
    {  // stage Whh slice: 16 local tiles (4 gates x 4 waves) x 8 ks x 1KB = 128KB
      short8* wl = (short8*)whh_lds;
#pragma unroll
      for (int k = 0; k < 32; k++) {
        int i = tid + 256 * k;
        int lane = i & 63, ks = (i >> 6) & 7, tl = i >> 9;
        int c = (tl >> 2) * 16 + 4 * gg + (tl & 3);
        wl[i] = WhhP[(c * 8 + ks) * 64 + lane];
      }
    }
    float bact[4];
#pragma unroll
    for (int g = 0; g < 4; g++) bact[g] = bias[g * 256 + U];
    __syncthreads();  // weights staged

    // hoisted B-fragments (static-indexed; LDS is the remat backing if not kept)
    const short8* WH = (const short8*)whh_lds;
    short8 rB[4][8];
#pragma unroll
    for (int g = 0; g < 4; g++)
#pragma unroll
      for (int ks = 0; ks < 8; ks++)
        rB[g][ks] = WH[((g * 4 + w) * 8 + ks) * 64 + l];
    short8 rX[4][2];
#pragma unroll
    for (int g = 0; g < 4; g++)
#pragma unroll
      for (int j = 0; j < 2; j++)
        rX[g][j] = WihP[((g * 16 + 4 * gg + w) * 2 + j) * 64 + l];

#pragma unroll 1
    for (int ti = 0; ti < TT; ++ti) {
      const int it = ph * TT + ti;
      const int t = ph ? (TT - 1 - ti) : ti;
      unsigned short* zc = zbb + (it & 1) * (16 * ZSTR);
      unsigned short* zn = zbb + ((it & 1) ^ 1) * (16 * ZSTR);

      // pre-spin: x fragments + 8 x-MFMAs (everything else waits on peers anyway)
      short8 aX0 = *(const short8*)&zc[ln * ZSTR + 256 + lk * 8];
      short8 aX1 = *(const short8*)&zc[ln * ZSTR + 288 + lk * 8];
      f32x4 acc[4];
#pragma unroll
      for (int g = 0; g < 4; g++) {
        acc[g] = f32x4{0.f, 0.f, 0.f, 0.f};
        acc[g] = __builtin_amdgcn_mfma_f32_16x16x32_bf16(aX0, rX[g][0], acc[g], 0, 0, 0);
        acc[g] = __builtin_amdgcn_mfma_f32_16x16x32_bf16(aX1, rX[g][1], acc[g], 0, 0, 0);
      }

      // spin on 6 peer words (tagged, relaxed agent — proven), unpack into zc
      if (it) {
        const u64t* base = hb + (size_t)(it & 1) * 16384;
        u64t v0 = 0, v1 = 0, v2 = 0, v3 = 0, v4 = 0, v5 = 0;
        bool d0 = false, d1 = false, d2 = false, d3 = false, d4 = false, d5 = false;
        do {
          if (!d0) { v0 = __hip_atomic_load(base + cidx[0], __ATOMIC_RELAXED, __HIP_MEMORY_SCOPE_AGENT);
                     d0 = ((u32t)v0 == (u32t)it); }
          if (!d1) { v1 = __hip_atomic_load(base + cidx[1], __ATOMIC_RELAXED, __HIP_MEMORY_SCOPE_AGENT);
                     d1 = ((u32t)v1 == (u32t)it); }
          if (!d2) { v2 = __hip_atomic_load(base + cidx[2], __ATOMIC_RELAXED, __HIP_MEMORY_SCOPE_AGENT);
                     d2 = ((u32t)v2 == (u32t)it); }
          if (!d3) { v3 = __hip_atomic_load(base + cidx[3], __ATOMIC_RELAXED, __HIP_MEMORY_SCOPE_AGENT);
                     d3 = ((u32t)v3 == (u32t)it); }
          if (!d4) { v4 = __hip_atomic_load(base + cidx[4], __ATOMIC_RELAXED, __HIP_MEMORY_SCOPE_AGENT);
                     d4 = ((u32t)v4 == (u32t)it); }
          if (!d5) { v5 = __hip_atomic_load(base + cidx[5], __ATOMIC_RELAXED, __HIP_MEMORY_SCOPE_AGENT);
                     d5 = ((u32t)v5 == (u32t)it); }
        } while (!(d0 && d1 && d2 && d3 && d4 && d5));
        zc[crow[0] * ZSTR + cU[0]] = (unsigned short)(v0 >> 32);
        zc[(crow[0] + 1) * ZSTR + cU[0]] = (unsigned short)(v0 >> 48);
        zc[crow[1] * ZSTR + cU[1]] = (unsigned short)(v1 >> 32);
        zc[(crow[1] + 1) * ZSTR + cU[1]] = (unsigned short)(v1 >> 48);
        zc[crow[2] * ZSTR + cU[2]] = (unsigned short)(v2 >> 32);
        zc[(crow[2] + 1) * ZSTR + cU[2]] = (unsigned short)(v2 >> 48);
        zc[crow[3] * ZSTR + cU[3]] = (unsigned short)(v3 >> 32);
        zc[(crow[3] + 1) * ZSTR + cU[3]] = (unsigned short)(v3 >> 48);
        zc[crow[4] * ZSTR + cU[4]] = (unsigned short)(v4 >> 32);
        zc[(crow[4] + 1) * ZSTR + cU[4]] = (unsigned short)(v4 >> 48);
        zc[crow[5] * ZSTR + cU[5]] = (unsigned short)(v5 >> 32);
        zc[(crow[5] + 1) * ZSTR + cU[5]] = (unsigned short)(v5 >> 48);
      }
      __syncthreads();  // B1: full z assembled

      // critical tail: 8 A-reads + 32 MFMA (B in regs / cheap LDS remat)
      short8 afr[8];
#pragma unroll
      for (int ks = 0; ks < 8; ks++)
        afr[ks] = *(const short8*)&zc[ln * ZSTR + ks * 32 + lk * 8];
#pragma unroll
      for (int ks = 0; ks < 8; ks++)
#pragma unroll
        for (int g = 0; g < 4; g++)
          acc[g] = __builtin_amdgcn_mfma_f32_16x16x32_bf16(afr[ks], rB[g][ks], acc[g], 0, 0, 0);

      // wave-local activation: lane holds i,f,g,o for unit U, rows 4lk+r
      unsigned short hu[4];
#pragma unroll
      for (int r = 0; r < 4; r++) {
        float gi = acc[0][r] + bact[0];
        float gf = acc[1][r] + bact[1];
        float gG = acc[2][r] + bact[2];
        float go = acc[3][r] + bact[3];
        float si = 1.f / (1.f + __expf(-gi));
        float sf = 1.f / (1.f + __expf(-gf));
        float tg = 1.f - 2.f / (__expf(2.f * gG) + 1.f);
        float so = 1.f / (1.f + __expf(-go));
        float cn = sf * creg[r] + si * tg;
        creg[r] = cn;
        float hn = so * (1.f - 2.f / (__expf(2.f * cn) + 1.f));
        hu[r] = f2b(hn);
      }

      {  // publish h(it+1) FIRST (peers' critical path)
        u64t* bp = hb + (size_t)((it + 1) & 1) * 16384;
        const u64t tag = (u64t)(u32t)(it + 1);
        __hip_atomic_store(bp + p0,     tag | ((u64t)((u32t)hu[0] | ((u32t)hu[1] << 16)) << 32),
                           __ATOMIC_RELAXED, __HIP_MEMORY_SCOPE_AGENT);
        __hip_atomic_store(bp + p0 + 1, tag | ((u64t)((u32t)hu[2] | ((u32t)hu[3] << 16)) << 32),
                           __ATOMIC_RELAXED, __HIP_MEMORY_SCOPE_AGENT);
      }

      // stage own h(it+1) into next zb
      zn[(4 * lk + 0) * ZSTR + U] = hu[0];
      zn[(4 * lk + 1) * ZSTR + U] = hu[1];
      zn[(4 * lk + 2) * ZSTR + U] = hu[2];
      zn[(4 * lk + 3) * ZSTR + U] = hu[3];

      // decoder output (rotating wave, LDS Wout): out[:,t] = h(it) @ Wout^T + bout
      if (ph == 1 && w == (ti & 3)) {
        const short8* WO = (const short8*)wout_lds;
        f32x4 oa = {0.f, 0.f, 0.f, 0.f};
#pragma unroll
        for (int ks = 0; ks < 8; ks++)
          oa = __builtin_amdgcn_mfma_f32_16x16x32_bf16(afr[ks], WO[ks * 64 + l], oa, 0, 0, 0);
#pragma unroll
        for (int r = 0; r < 4; r++)
          out[((size_t)(b0 + 4 * lk + r) * TT + t) * FF + 16 * gg + ln] = oa[r] + bo_;
      }

      // stage x(t+1) into next zb; prefetch x(t+2)
      *(u32t*)&zn[xrow * ZSTR + HH + xf]     = pk2(xv.x, xv.y);
      *(u32t*)&zn[xrow * ZSTR + HH + xf + 2] = pk2(xv.z, xv.w);
      {
        int it2 = it + 2; if (it2 >= 2 * TT) it2 = 0;
        int t2 = (it2 < TT) ? it2 : (2 * TT - 1 - it2);
        xv = *(const float4*)(xrp + (size_t)t2 * FF);
      }
      __syncthreads();  // B2: next zb staged; zc reads done
    }
  }
}

extern "C" void kernel_launch(void* const* d_in, const int* in_sizes, int n_in,
                              void* d_out, int out_size, void* d_ws, size_t ws_size,
                              hipStream_t stream) {
  const float* ts    = (const float*)d_in[0];
  const float* Wih_e = (const float*)d_in[1];
  const float* Whh_e = (const float*)d_in[2];
  const float* b_e   = (const float*)d_in[3];
  const float* Wih_d = (const float*)d_in[4];
  const float* Whh_d = (const float*)d_in[5];
  const float* b_d   = (const float*)d_in[6];
  const float* Wout  = (const float*)d_in[7];
  const float* bout  = (const float*)d_in[8];
  unsigned short* ws = (unsigned short*)d_ws;
  float* out = (float*)d_out;
  u64t* hb = (u64t*)((char*)d_ws + WS_HB_B);

  const int ldsBytes = (10496 + 4096 + 65536) * 2;  // 160256 B
  (void)hipFuncSetAttribute((const void*)lstm_kernel,
                            hipFuncAttributeMaxDynamicSharedMemorySize, ldsBytes);

  prep_kernel<<<328, 256, 0, stream>>>(Wih_e, Whh_e, Wih_d, Whh_d, Wout, ws);
  init_hb<<<64, 512, 0, stream>>>(hb);
  lstm_kernel<<<32, 256, ldsBytes, stream>>>(ts, b_e, b_d, bout, ws, out, hb);
}